// Round 3
// baseline (172.273 us; speedup 1.0000x reference)
//
#include <hip/hip_runtime.h>
#include <math.h>

#define N 1024
#define B_ 8
#define T_ 512
#define NREP 4
#define CHUNKS 64

// ws layout (float index)
#define OFF_SF      0        // 1024 x float2 (element shift factor)
#define OFF_TA      2048     // 16(k1) x 64(lane) x float2 : W_1024^{lane*k1}
#define OFF_TB      6144     // 16(k2) x 4(n3) x float2    : W_64^{n3*k2}
#define OFF_ROWSUM  6272     // 8 x 1024
#define ZERO_START  14464
#define OFF_COLSUMM 14464    // 1024
#define OFF_SUMM2   15488
#define OFF_MAXM    15489
#define OFF_SUMMT   15496    // 8
#define OFF_SUMTT   15504    // 8
#define OFF_COLT    15520    // 8 batches x NREP x 1024
#define WS_END      (OFF_COLT + B_ * NREP * N)

__device__ __forceinline__ float wave_sum(float v) {
    #pragma unroll
    for (int o = 32; o > 0; o >>= 1) v += __shfl_down(v, o, 64);
    return v;
}
__device__ __forceinline__ float wave_max(float v) {
    #pragma unroll
    for (int o = 32; o > 0; o >>= 1) v = fmaxf(v, __shfl_down(v, o, 64));
    return v;
}

__device__ __forceinline__ void cmul(float& xr, float& xi, float wr, float wi) {
    float r = xr * wr - xi * wi;
    float i = xr * wi + xi * wr;
    xr = r; xi = i;
}

// 4-pt DFT (W4 = -i), outputs in natural order in place
__device__ __forceinline__ void dft4(float& r0, float& i0, float& r1, float& i1,
                                     float& r2, float& i2, float& r3, float& i3) {
    float e0r = r0 + r2, e0i = i0 + i2;
    float e1r = r0 - r2, e1i = i0 - i2;
    float e2r = r1 + r3, e2i = i1 + i3;
    float e3r = r1 - r3, e3i = i1 - i3;
    r0 = e0r + e2r; i0 = e0i + e2i;
    r2 = e0r - e2r; i2 = e0i - e2i;
    r1 = e1r + e3i; i1 = e1i - e3r;   // e1 - i*e3
    r3 = e1r - e3i; i3 = e1i + e3r;   // e1 + i*e3
}

// 16-pt DFT over register index n (natural order in).
// Output: slot r = 4c+d holds S[k = c+4d]  (digit-swapped order).
__device__ __forceinline__ void dft16(float xr[16], float xi[16]) {
    #pragma unroll
    for (int b = 0; b < 4; ++b)
        dft4(xr[b], xi[b], xr[4 + b], xi[4 + b], xr[8 + b], xi[8 + b], xr[12 + b], xi[12 + b]);
    const float C1 = 0.9238795325112867f, S1 = 0.3826834323650898f;
    const float C2 = 0.7071067811865476f;
    // slot[4c+b] *= W16^{b*c}
    cmul(xr[5],  xi[5],   C1, -S1);   // bc=1
    cmul(xr[6],  xi[6],   C2, -C2);   // bc=2
    cmul(xr[7],  xi[7],   S1, -C1);   // bc=3
    cmul(xr[9],  xi[9],   C2, -C2);   // bc=2
    { float t = xr[10]; xr[10] = xi[10]; xi[10] = -t; }  // bc=4 : * (0,-1)
    cmul(xr[11], xi[11], -C2, -C2);   // bc=6
    cmul(xr[13], xi[13],  S1, -C1);   // bc=3
    cmul(xr[14], xi[14], -C2, -C2);   // bc=6
    cmul(xr[15], xi[15], -C1,  S1);   // bc=9
    #pragma unroll
    for (int c = 0; c < 4; ++c)
        dft4(xr[4 * c], xi[4 * c], xr[4 * c + 1], xi[4 * c + 1],
             xr[4 * c + 2], xi[4 * c + 2], xr[4 * c + 3], xi[4 * c + 3]);
}

// DPP quad-perm move (cross-lane within each 4-lane quad), VALU-only
template<int CTRL>
__device__ __forceinline__ float dppf(float x) {
    return __int_as_float(__builtin_amdgcn_update_dpp(
        0, __float_as_int(x), CTRL, 0xF, 0xF, true));
}
#define DPP_XOR1 0xB1   // quad_perm [1,0,3,2]
#define DPP_XOR2 0x4E   // quad_perm [2,3,0,1]

// tables + zero accumulators: 12 blocks x 256 threads
__global__ __launch_bounds__(256) void k_prep(float* ws, float* out) {
    const int e = blockIdx.x * 256 + threadIdx.x;   // 0..3071
    if (e < 1024) {
        double ang = -2.0 * 337.927 * 1.5 * (double)(e - 512);
        double s, c;
        sincos(ang, &s, &c);
        ws[OFF_SF + 2 * e]     = (float)c;
        ws[OFF_SF + 2 * e + 1] = (float)s;
    } else if (e < 2048) {
        int e2 = e - 1024;
        int k1 = e2 >> 6, uu = e2 & 63;
        double ang = -2.0 * M_PI * (double)(uu * k1) / 1024.0;
        double s, c;
        sincos(ang, &s, &c);
        ws[OFF_TA + 2 * e2]     = (float)c;
        ws[OFF_TA + 2 * e2 + 1] = (float)s;
    } else if (e < 2112) {
        int e2 = e - 2048;
        int k2 = e2 >> 2, n3 = e2 & 3;
        double ang = -2.0 * M_PI * (double)(n3 * k2) / 64.0;
        double s, c;
        sincos(ang, &s, &c);
        ws[OFF_TB + 2 * e2]     = (float)c;
        ws[OFF_TB + 2 * e2 + 1] = (float)s;
    }
    for (int j = ZERO_START + e; j < WS_END; j += 12 * 256) ws[j] = 0.f;
    if (e == 0) out[0] = 0.f;
}

// grid (64, 8): batch b, chunk cnk covers rows 8*cnk..8*cnk+7, ONE ROW PER WAVE.
// Wave-private 1024-pt FFT: radix-16(reg) -> LDS transpose -> radix-16(reg)
// -> radix-4 via DPP quad shuffles. (cnk=0,wid=0) also does m=512.
// Batch-0 waves fold in the M statistics (each reads every M element once).
__global__ __launch_bounds__(T_, 4) void k_row(const float* __restrict__ pred,
                                               const float* __restrict__ M,
                                               float* __restrict__ ws) {
    __shared__ float2 Y2[N];        // y interleaved (8 KB)
    __shared__ float2 TP[8][N];     // per-wave transpose buffers (64 KB)
    __shared__ float2 TB2[64];      // W_64^{n3*k2}
    __shared__ float redf[4][8];    // block reduce: mt, tt, sq, mx per wave
    const int t = threadIdx.x;
    const int cnk = blockIdx.x;
    const int b = blockIdx.y;
    const int wid = t >> 6, u = t & 63;

    // ---- staging: y into LDS (interleaved), TB into LDS ----
    {
        const float* pr = pred + (size_t)b * 2 * N;
        float2 re = *(const float2*)(pr + 2 * t);
        float2 im = *(const float2*)(pr + N + 2 * t);
        Y2[2 * t]     = make_float2(re.x, im.x);
        Y2[2 * t + 1] = make_float2(re.y, im.y);
        if (t < 64) TB2[t] = ((const float2*)(ws + OFF_TB))[t];
    }
    __syncthreads();   // the only pre-epilogue block barrier

    const int k1u = u >> 2;
    const int n3 = u & 3;
    const int k3 = ((u & 1) << 1) | ((u >> 1) & 1);   // bitrev2(n3)
    const int clane = (k1u | (k3 << 8)) ^ 512;        // output column base (incl. fftshift)
    const bool hi2 = (u & 2) != 0;
    const bool odd = (u & 1) != 0;
    float2* tp = TP[wid];
    const float2* sf2 = (const float2*)(ws + OFF_SF);
    const float2* taT = (const float2*)(ws + OFF_TA);

    float mtl = 0.f, ttl = 0.f, sql = 0.f, mxl = 0.f;
    const bool dostats = (b == 0);
    const int nrow = (cnk == 0 && wid == 0) ? 2 : 1;

    for (int rr = 0; rr < nrow; ++rr) {
        const int m = (rr == 0) ? (cnk * 8 + wid) : 512;
        const int mm = (N - m) & (N - 1);
        const bool domm = (mm != m);
        const float w = domm ? 2.f : 1.f;

        // prefetch M rows into registers (addresses independent of FFT)
        const float* Mrow  = M + (size_t)m * N + clane;
        const float* Mrow2 = M + (size_t)mm * N + clane;
        float mr[16], mr2[16];
        #pragma unroll
        for (int r = 0; r < 16; ++r) {
            int k2 = ((r & 3) << 2) | (r >> 2);
            mr[r] = Mrow[k2 << 4];
        }
        if (domm) {
            #pragma unroll
            for (int r = 0; r < 16; ++r) {
                int k2 = ((r & 3) << 2) | (r >> 2);
                mr2[r] = Mrow2[k2 << 4];
            }
        } else {
            #pragma unroll
            for (int r = 0; r < 16; ++r) mr2[r] = 0.f;
        }

        float xr[16], xi[16];
        // phase A: product (y[j]*sf[j]*y[s]) + radix-16 over n1
        const int sbase = (u - m + 512) & (N - 1);
        #pragma unroll
        for (int n1 = 0; n1 < 16; ++n1) {
            int j = (n1 << 6) + u;
            float2 yj = Y2[j];
            float2 sv = sf2[j];                 // L2-hot global table
            int s = (sbase + (n1 << 6)) & (N - 1);
            float2 yb = Y2[s];
            float ar = yj.x * sv.x - yj.y * sv.y;
            float ai = yj.x * sv.y + yj.y * sv.x;
            xr[n1] = ar * yb.x - ai * yb.y;
            xi[n1] = ar * yb.y + ai * yb.x;
        }
        dft16(xr, xi);
        #pragma unroll
        for (int r = 1; r < 16; ++r) {
            int k1 = ((r & 3) << 2) | (r >> 2);
            float2 wv = taT[(k1 << 6) + u];     // L2-hot global table
            cmul(xr[r], xi[r], wv.x, wv.y);
        }

        // wave-local transpose through per-wave LDS buffer (XOR-swizzled)
        asm volatile("s_waitcnt lgkmcnt(0)" ::: "memory");   // WAR vs prev row's reads
        #pragma unroll
        for (int r = 0; r < 16; ++r) {
            int k1 = ((r & 3) << 2) | (r >> 2);
            int el = (k1 << 6) | (((k1u ^ k1) & 15) << 2) | n3;
            tp[el] = make_float2(xr[r], xi[r]);
        }
        asm volatile("s_waitcnt lgkmcnt(0)" ::: "memory");   // RAW write->read
        #pragma unroll
        for (int n2 = 0; n2 < 16; ++n2) {
            int el = (k1u << 6) | (((n2 ^ k1u) & 15) << 2) | n3;
            float2 v = tp[el];
            xr[n2] = v.x; xi[n2] = v.y;
        }

        // phase B: radix-16 over n2 + W_64^{n3*k2}
        dft16(xr, xi);
        #pragma unroll
        for (int r = 1; r < 16; ++r) {
            int k2 = ((r & 3) << 2) | (r >> 2);
            float2 wv = TB2[(k2 << 2) | n3];
            cmul(xr[r], xi[r], wv.x, wv.y);
        }

        // phase C: radix-4 across quad lanes (DPP) + magnitude + reductions
        float* colT = ws + OFF_COLT + (size_t)(b * NREP + (cnk & (NREP - 1))) * N;
        const float w225 = w * 2.25f;
        float rs = 0.f;
        #pragma unroll
        for (int r = 0; r < 16; ++r) {
            int k2 = ((r & 3) << 2) | (r >> 2);
            float ar = xr[r], ai = xi[r];
            float br = dppf<DPP_XOR2>(ar), bi = dppf<DPP_XOR2>(ai);
            float zr = hi2 ? (br - ar) : (ar + br);
            float zi = hi2 ? (bi - ai) : (ai + bi);
            float qr = dppf<DPP_XOR1>(zr), qi = dppf<DPP_XOR1>(zi);
            float Xr = odd ? (qr - (hi2 ? zi : zr)) : (zr + (hi2 ? qi : qr));
            float Xi = odd ? (qi + (hi2 ? zr : -zi)) : (zi + (hi2 ? -qr : qi));
            float mag2 = Xr * Xr + Xi * Xi;
            float v = 1.5f * sqrtf(mag2);
            rs  += v;
            ttl += w225 * mag2;                 // w * v^2
            float ms = mr[r] + mr2[r];
            mtl += ms * v;
            atomicAdd(&colT[clane + (k2 << 4)], w * v);
            if (dostats) {
                sql += mr[r] * mr[r] + mr2[r] * mr2[r];
                mxl = fmaxf(mxl, fmaxf(mr[r], mr2[r]));
                atomicAdd(&ws[OFF_COLSUMM + clane + (k2 << 4)], ms);
            }
        }
        rs = wave_sum(rs);
        if (u == 0) {
            ws[OFF_ROWSUM + (size_t)b * N + m] = rs;
            if (domm) ws[OFF_ROWSUM + (size_t)b * N + mm] = rs;
        }
    }

    // block epilogue: one atomic per block for MT/TT (and stats for b==0)
    mtl = wave_sum(mtl);
    ttl = wave_sum(ttl);
    if (dostats) { sql = wave_sum(sql); mxl = wave_max(mxl); }
    if (u == 0) { redf[0][wid] = mtl; redf[1][wid] = ttl; redf[2][wid] = sql; redf[3][wid] = mxl; }
    __syncthreads();
    if (t == 0) {
        float smt = 0.f, stt = 0.f, ssq = 0.f, smx = 0.f;
        #pragma unroll
        for (int i = 0; i < 8; ++i) {
            smt += redf[0][i]; stt += redf[1][i];
            ssq += redf[2][i]; smx = fmaxf(smx, redf[3][i]);
        }
        atomicAdd(&ws[OFF_SUMMT + b], smt);
        atomicAdd(&ws[OFF_SUMTT + b], stt);
        if (dostats) {
            atomicAdd(&ws[OFF_SUMM2], ssq);
            atomicMax((unsigned int*)ws + OFF_MAXM, __float_as_uint(smx));
        }
    }
}

__global__ __launch_bounds__(256) void k_final(float* ws, float* out) {
    __shared__ double redn[4], redd[4];
    const int b = blockIdx.x;
    const int t = threadIdx.x;
    const int wid = t >> 6, lane = t & 63;
    const float* rowsum = ws + OFF_ROWSUM + (size_t)b * N;
    double num = 0.0, den = 0.0;
    #pragma unroll
    for (int q = 0; q < 4; ++q) {
        int j = t + 256 * q;
        double r = (double)rowsum[j];
        float ct = 0.f;
        #pragma unroll
        for (int rep = 0; rep < NREP; ++rep)
            ct += ws[OFF_COLT + (size_t)(b * NREP + rep) * N + j];
        num += (double)ws[OFF_COLSUMM + j] * r;
        den += (double)ct * r;
    }
    #pragma unroll
    for (int o = 32; o > 0; o >>= 1) {
        num += __shfl_down(num, o, 64);
        den += __shfl_down(den, o, 64);
    }
    if (lane == 0) { redn[wid] = num; redd[wid] = den; }
    __syncthreads();
    if (t == 0) {
        double NUM = redn[0] + redn[1] + redn[2] + redn[3];
        double DEN = redd[0] + redd[1] + redd[2] + redd[3];
        double mu = NUM / DEN;
        double r = (double)ws[OFF_SUMM2] - 2.0 * mu * (double)ws[OFF_SUMMT + b]
                 + mu * mu * (double)ws[OFF_SUMTT + b];
        float mx = ws[OFF_MAXM];  // float bits written via uint atomicMax
        double norm = 1048576.0 * (double)mx * (double)mx;
        atomicAdd(out, (float)(sqrt(r / norm) / 8.0));
    }
}

extern "C" void kernel_launch(void* const* d_in, const int* in_sizes, int n_in,
                              void* d_out, int out_size, void* d_ws, size_t ws_size,
                              hipStream_t stream) {
    const float* pred = (const float*)d_in[0];   // [8, 2048]
    const float* M = (const float*)d_in[2];      // [1024, 1024]
    float* ws = (float*)d_ws;
    float* out = (float*)d_out;

    k_prep<<<12, 256, 0, stream>>>(ws, out);
    dim3 grid(CHUNKS, B_);
    k_row<<<grid, T_, 0, stream>>>(pred, M, ws);
    k_final<<<B_, 256, 0, stream>>>(ws, out);
}

// Round 4
// 100.392 us; speedup vs baseline: 1.7160x; 1.7160x over previous
//
#include <hip/hip_runtime.h>
#include <math.h>

#define N 1024
#define B_ 8
#define T_ 512
#define NREP 4
#define CHUNKS 64

// ws layout (float index)
#define OFF_SF      0        // 1024 x float2 (element shift factor)
#define OFF_TA      2048     // 16(k1) x 64(lane) x float2 : W_1024^{lane*k1}
#define OFF_TB      4096     // 16(k2) x 4(n3) x float2    : W_64^{n3*k2}
#define OFF_ROWSUM  4224     // 8 x 1024
#define ZERO_START  12416
#define OFF_COLSUMM 12416    // 1024
#define OFF_SUMM2   13440
#define OFF_MAXM    13441
#define OFF_SUMMT   13448    // 8
#define OFF_SUMTT   13456    // 8
#define OFF_COLT    13464    // 8 batches x NREP x 1024
#define WS_END      (OFF_COLT + B_ * NREP * N)

__device__ __forceinline__ float wave_sum(float v) {
    #pragma unroll
    for (int o = 32; o > 0; o >>= 1) v += __shfl_down(v, o, 64);
    return v;
}
__device__ __forceinline__ float wave_max(float v) {
    #pragma unroll
    for (int o = 32; o > 0; o >>= 1) v = fmaxf(v, __shfl_down(v, o, 64));
    return v;
}

__device__ __forceinline__ void cmul(float& xr, float& xi, float wr, float wi) {
    float r = xr * wr - xi * wi;
    float i = xr * wi + xi * wr;
    xr = r; xi = i;
}

// 4-pt DFT (W4 = -i), outputs in natural order in place
__device__ __forceinline__ void dft4(float& r0, float& i0, float& r1, float& i1,
                                     float& r2, float& i2, float& r3, float& i3) {
    float e0r = r0 + r2, e0i = i0 + i2;
    float e1r = r0 - r2, e1i = i0 - i2;
    float e2r = r1 + r3, e2i = i1 + i3;
    float e3r = r1 - r3, e3i = i1 - i3;
    r0 = e0r + e2r; i0 = e0i + e2i;
    r2 = e0r - e2r; i2 = e0i - e2i;
    r1 = e1r + e3i; i1 = e1i - e3r;   // e1 - i*e3
    r3 = e1r - e3i; i3 = e1i + e3r;   // e1 + i*e3
}

// 16-pt DFT over register index n (natural order in).
// Output: slot r = 4c+d holds S[k = c+4d]  (digit-swapped order).
__device__ __forceinline__ void dft16(float xr[16], float xi[16]) {
    #pragma unroll
    for (int b = 0; b < 4; ++b)
        dft4(xr[b], xi[b], xr[4 + b], xi[4 + b], xr[8 + b], xi[8 + b], xr[12 + b], xi[12 + b]);
    const float C1 = 0.9238795325112867f, S1 = 0.3826834323650898f;
    const float C2 = 0.7071067811865476f;
    // slot[4c+b] *= W16^{b*c}
    cmul(xr[5],  xi[5],   C1, -S1);   // bc=1
    cmul(xr[6],  xi[6],   C2, -C2);   // bc=2
    cmul(xr[7],  xi[7],   S1, -C1);   // bc=3
    cmul(xr[9],  xi[9],   C2, -C2);   // bc=2
    { float t = xr[10]; xr[10] = xi[10]; xi[10] = -t; }  // bc=4 : * (0,-1)
    cmul(xr[11], xi[11], -C2, -C2);   // bc=6
    cmul(xr[13], xi[13],  S1, -C1);   // bc=3
    cmul(xr[14], xi[14], -C2, -C2);   // bc=6
    cmul(xr[15], xi[15], -C1,  S1);   // bc=9
    #pragma unroll
    for (int c = 0; c < 4; ++c)
        dft4(xr[4 * c], xi[4 * c], xr[4 * c + 1], xi[4 * c + 1],
             xr[4 * c + 2], xi[4 * c + 2], xr[4 * c + 3], xi[4 * c + 3]);
}

// DPP quad-perm move (cross-lane within each 4-lane quad), VALU-only
template<int CTRL>
__device__ __forceinline__ float dppf(float x) {
    return __int_as_float(__builtin_amdgcn_update_dpp(
        0, __float_as_int(x), CTRL, 0xF, 0xF, true));
}
#define DPP_XOR1 0xB1   // quad_perm [1,0,3,2]
#define DPP_XOR2 0x4E   // quad_perm [2,3,0,1]

// tables + zero accumulators: 12 blocks x 256 threads
__global__ __launch_bounds__(256) void k_prep(float* ws, float* out) {
    const int e = blockIdx.x * 256 + threadIdx.x;   // 0..3071
    if (e < 1024) {
        double ang = -2.0 * 337.927 * 1.5 * (double)(e - 512);
        double s, c;
        sincos(ang, &s, &c);
        ws[OFF_SF + 2 * e]     = (float)c;
        ws[OFF_SF + 2 * e + 1] = (float)s;
    } else if (e < 2048) {
        int e2 = e - 1024;
        int k1 = e2 >> 6, uu = e2 & 63;
        double ang = -2.0 * M_PI * (double)(uu * k1) / 1024.0;
        double s, c;
        sincos(ang, &s, &c);
        ws[OFF_TA + 2 * e2]     = (float)c;
        ws[OFF_TA + 2 * e2 + 1] = (float)s;
    } else if (e < 2112) {
        int e2 = e - 2048;
        int k2 = e2 >> 2, n3 = e2 & 3;
        double ang = -2.0 * M_PI * (double)(n3 * k2) / 64.0;
        double s, c;
        sincos(ang, &s, &c);
        ws[OFF_TB + 2 * e2]     = (float)c;
        ws[OFF_TB + 2 * e2 + 1] = (float)s;
    }
    for (int j = ZERO_START + e; j < WS_END; j += 12 * 256) ws[j] = 0.f;
    if (e == 0) out[0] = 0.f;
}

// grid (64, 9):
//   y == 0 : M-stats (64 blocks, 16 rows each) — dispatched FIRST, overlaps FFT work
//   y >= 1 : batch b=y-1, chunk cnk covers rows 8*cnk..8*cnk+7, ONE ROW PER WAVE.
// Wave-private 1024-pt FFT: radix-16(reg) -> LDS transpose -> radix-16(reg)
// -> radix-4 via DPP quad shuffles. (cnk=0,wid=0) also does m=512.
// NOTE: no __launch_bounds__ min-occupancy — that caused 64-VGPR caps + spills
// (r2: 84 VGPR/26MB scratch, r3: 64 VGPR/200MB scratch). LDS (~77KB) limits us
// to 2 blocks/CU = 4 waves/EU, so cap the allocator's occupancy target there.
__global__ __attribute__((amdgpu_flat_work_group_size(T_, T_), amdgpu_waves_per_eu(2, 4)))
void k_row(const float* __restrict__ pred,
           const float* __restrict__ M,
           float* __restrict__ ws) {
    __shared__ float2 Y2[N];        // y interleaved (8 KB)
    __shared__ float2 TP[8][N];     // per-wave transpose buffers (64 KB)
    __shared__ float  colAcc[N];    // block column accumulator (4 KB)
    __shared__ float2 TB2[64];      // W_64^{n3*k2}
    __shared__ float redf[2][8];    // block reduce
    const int t = threadIdx.x;
    const int cnk = blockIdx.x;
    const int y = blockIdx.y;
    const int wid = t >> 6, u = t & 63;

    if (y == 0) {
        // ---- M-stats slice: rows 16*cnk..16*cnk+15, thread t covers cols t, t+512
        const int r0 = cnk * 16;
        float cs0 = 0.f, cs1 = 0.f, sq = 0.f, mx = 0.f;
        for (int r = 0; r < 16; ++r) {
            const float* row = M + (size_t)(r0 + r) * N;
            float v0 = row[t], v1 = row[t + 512];
            cs0 += v0; cs1 += v1;
            sq += v0 * v0 + v1 * v1;
            mx = fmaxf(mx, fmaxf(v0, v1));
        }
        atomicAdd(&ws[OFF_COLSUMM + t],       cs0);
        atomicAdd(&ws[OFF_COLSUMM + t + 512], cs1);
        sq = wave_sum(sq);
        mx = wave_max(mx);
        if (u == 0) { redf[0][wid] = sq; redf[1][wid] = mx; }
        __syncthreads();
        if (t == 0) {
            float ssq = 0.f, smx = 0.f;
            #pragma unroll
            for (int i = 0; i < 8; ++i) { ssq += redf[0][i]; smx = fmaxf(smx, redf[1][i]); }
            atomicAdd(&ws[OFF_SUMM2], ssq);
            atomicMax((unsigned int*)ws + OFF_MAXM, __float_as_uint(smx));
        }
        return;
    }
    const int b = y - 1;

    // ---- staging: y into LDS (interleaved), TB into LDS, colAcc zero ----
    {
        const float* pr = pred + (size_t)b * 2 * N;
        float2 re = *(const float2*)(pr + 2 * t);
        float2 im = *(const float2*)(pr + N + 2 * t);
        Y2[2 * t]     = make_float2(re.x, im.x);
        Y2[2 * t + 1] = make_float2(re.y, im.y);
        colAcc[t] = 0.f;
        colAcc[t + 512] = 0.f;
        if (t < 64) TB2[t] = ((const float2*)(ws + OFF_TB))[t];
    }
    __syncthreads();

    const int k1u = u >> 2;
    const int n3 = u & 3;
    const int k3 = ((u & 1) << 1) | ((u >> 1) & 1);   // bitrev2(n3)
    const int clane = (k1u | (k3 << 8)) ^ 512;        // output column base (incl. fftshift)
    const bool hi2 = (u & 2) != 0;
    const bool odd = (u & 1) != 0;
    float2* tp = TP[wid];
    const float2* sf2 = (const float2*)(ws + OFF_SF);
    const float2* taT = (const float2*)(ws + OFF_TA);

    float mtl = 0.f, ttl = 0.f;
    const int nrow = (cnk == 0 && wid == 0) ? 2 : 1;

    for (int rr = 0; rr < nrow; ++rr) {
        const int m = (rr == 0) ? (cnk * 8 + wid) : 512;
        const int mm = (N - m) & (N - 1);
        const bool domm = (mm != m);
        const float w = domm ? 2.f : 1.f;
        const float mmw = domm ? 1.f : 0.f;

        float xr[16], xi[16];
        // phase A: product (y[j]*sf[j]*y[s]) + radix-16 over n1
        const int sbase = (u - m + 512) & (N - 1);
        #pragma unroll
        for (int n1 = 0; n1 < 16; ++n1) {
            int j = (n1 << 6) + u;
            float2 yj = Y2[j];
            float2 sv = sf2[j];                 // L2-hot global table
            int s = (sbase + (n1 << 6)) & (N - 1);
            float2 yb = Y2[s];
            float ar = yj.x * sv.x - yj.y * sv.y;
            float ai = yj.x * sv.y + yj.y * sv.x;
            xr[n1] = ar * yb.x - ai * yb.y;
            xi[n1] = ar * yb.y + ai * yb.x;
        }
        dft16(xr, xi);
        #pragma unroll
        for (int r = 1; r < 16; ++r) {
            int k1 = ((r & 3) << 2) | (r >> 2);
            float2 wv = taT[(k1 << 6) + u];     // L2-hot global table
            cmul(xr[r], xi[r], wv.x, wv.y);
        }

        // wave-local transpose through per-wave LDS buffer (XOR-swizzled)
        asm volatile("s_waitcnt lgkmcnt(0)" ::: "memory");   // WAR vs prev row's reads
        #pragma unroll
        for (int r = 0; r < 16; ++r) {
            int k1 = ((r & 3) << 2) | (r >> 2);
            int el = (k1 << 6) | (((k1u ^ k1) & 15) << 2) | n3;
            tp[el] = make_float2(xr[r], xi[r]);
        }
        asm volatile("s_waitcnt lgkmcnt(0)" ::: "memory");   // RAW write->read
        #pragma unroll
        for (int n2 = 0; n2 < 16; ++n2) {
            int el = (k1u << 6) | (((n2 ^ k1u) & 15) << 2) | n3;
            float2 v = tp[el];
            xr[n2] = v.x; xi[n2] = v.y;
        }

        // phase B: radix-16 over n2 + W_64^{n3*k2}
        dft16(xr, xi);
        #pragma unroll
        for (int r = 1; r < 16; ++r) {
            int k2 = ((r & 3) << 2) | (r >> 2);
            float2 wv = TB2[(k2 << 2) | n3];
            cmul(xr[r], xi[r], wv.x, wv.y);
        }

        // phase C: radix-4 across quad lanes (DPP) + magnitude + reductions.
        // M loaded inline (branchless mirror via mmw) — no persistent arrays.
        const float* Mrow  = M + (size_t)m * N + clane;
        const float* Mrow2 = M + (size_t)mm * N + clane;
        const float w225 = w * 2.25f;
        float rs = 0.f;
        #pragma unroll
        for (int r = 0; r < 16; ++r) {
            int k2 = ((r & 3) << 2) | (r >> 2);
            float ar = xr[r], ai = xi[r];
            float br = dppf<DPP_XOR2>(ar), bi = dppf<DPP_XOR2>(ai);
            float zr = hi2 ? (br - ar) : (ar + br);
            float zi = hi2 ? (bi - ai) : (ai + bi);
            float qr = dppf<DPP_XOR1>(zr), qi = dppf<DPP_XOR1>(zi);
            float Xr = odd ? (qr - (hi2 ? zi : zr)) : (zr + (hi2 ? qi : qr));
            float Xi = odd ? (qi + (hi2 ? zr : -zi)) : (zi + (hi2 ? -qr : qi));
            float mag2 = Xr * Xr + Xi * Xi;
            float v = 1.5f * sqrtf(mag2);
            rs  += v;
            ttl += w225 * mag2;                 // w * v^2
            float ms = Mrow[k2 << 4] + mmw * Mrow2[k2 << 4];
            mtl += ms * v;
            int cc = clane + (k2 << 4);
            atomicAdd(&colAcc[cc ^ ((cc >> 4) & 16)], w * v);  // 2-way bank alias: free
        }
        rs = wave_sum(rs);
        if (u == 0) {
            ws[OFF_ROWSUM + (size_t)b * N + m] = rs;
            if (domm) ws[OFF_ROWSUM + (size_t)b * N + mm] = rs;
        }
    }

    // block epilogue: MT/TT block-reduce + colAcc flush (1 global atomic/column)
    mtl = wave_sum(mtl);
    ttl = wave_sum(ttl);
    if (u == 0) { redf[0][wid] = mtl; redf[1][wid] = ttl; }
    __syncthreads();
    if (t == 0) {
        float smt = 0.f, stt = 0.f;
        #pragma unroll
        for (int i = 0; i < 8; ++i) { smt += redf[0][i]; stt += redf[1][i]; }
        atomicAdd(&ws[OFF_SUMMT + b], smt);
        atomicAdd(&ws[OFF_SUMTT + b], stt);
    }
    float* colT = ws + OFF_COLT + (size_t)(b * NREP + (cnk & (NREP - 1))) * N;
    {
        int j = t;
        atomicAdd(&colT[j], colAcc[j ^ ((j >> 4) & 16)]);
        j = t + 512;
        atomicAdd(&colT[j], colAcc[j ^ ((j >> 4) & 16)]);
    }
}

__global__ __launch_bounds__(256) void k_final(float* ws, float* out) {
    __shared__ double redn[4], redd[4];
    const int b = blockIdx.x;
    const int t = threadIdx.x;
    const int wid = t >> 6, lane = t & 63;
    const float* rowsum = ws + OFF_ROWSUM + (size_t)b * N;
    double num = 0.0, den = 0.0;
    #pragma unroll
    for (int q = 0; q < 4; ++q) {
        int j = t + 256 * q;
        double r = (double)rowsum[j];
        float ct = 0.f;
        #pragma unroll
        for (int rep = 0; rep < NREP; ++rep)
            ct += ws[OFF_COLT + (size_t)(b * NREP + rep) * N + j];
        num += (double)ws[OFF_COLSUMM + j] * r;
        den += (double)ct * r;
    }
    #pragma unroll
    for (int o = 32; o > 0; o >>= 1) {
        num += __shfl_down(num, o, 64);
        den += __shfl_down(den, o, 64);
    }
    if (lane == 0) { redn[wid] = num; redd[wid] = den; }
    __syncthreads();
    if (t == 0) {
        double NUM = redn[0] + redn[1] + redn[2] + redn[3];
        double DEN = redd[0] + redd[1] + redd[2] + redd[3];
        double mu = NUM / DEN;
        double r = (double)ws[OFF_SUMM2] - 2.0 * mu * (double)ws[OFF_SUMMT + b]
                 + mu * mu * (double)ws[OFF_SUMTT + b];
        float mx = ws[OFF_MAXM];  // float bits written via uint atomicMax
        double norm = 1048576.0 * (double)mx * (double)mx;
        atomicAdd(out, (float)(sqrt(r / norm) / 8.0));
    }
}

extern "C" void kernel_launch(void* const* d_in, const int* in_sizes, int n_in,
                              void* d_out, int out_size, void* d_ws, size_t ws_size,
                              hipStream_t stream) {
    const float* pred = (const float*)d_in[0];   // [8, 2048]
    const float* M = (const float*)d_in[2];      // [1024, 1024]
    float* ws = (float*)d_ws;
    float* out = (float*)d_out;

    k_prep<<<12, 256, 0, stream>>>(ws, out);
    dim3 grid(CHUNKS, B_ + 1);
    k_row<<<grid, T_, 0, stream>>>(pred, M, ws);
    k_final<<<B_, 256, 0, stream>>>(ws, out);
}